// Round 8
// baseline (126.745 us; speedup 1.0000x reference)
//
#include <hip/hip_runtime.h>

typedef float f32x4 __attribute__((ext_vector_type(4)));
typedef __bf16 bf16x8 __attribute__((ext_vector_type(8)));
typedef unsigned short u16;

__device__ __forceinline__ f32x4 mfma16(bf16x8 a, bf16x8 b, f32x4 c) {
  return __builtin_amdgcn_mfma_f32_16x16x32_bf16(a, b, c, 0, 0, 0);
}

__device__ __forceinline__ void gll16(const void* g, void* l) {
  __builtin_amdgcn_global_load_lds(
      (const __attribute__((address_space(1))) void*)g,
      (__attribute__((address_space(3))) void*)l, 16, 0, 0);
}

// ---------------- f32 -> bf16 convert ----------------
__global__ void cvt_kernel(const float* __restrict__ in, __bf16* __restrict__ out, int n8) {
  int idx = blockIdx.x * blockDim.x + threadIdx.x;
  int stride = gridDim.x * blockDim.x;
  for (int i = idx; i < n8; i += stride) {
    const float* p = in + (size_t)i * 8;
    f32x4 a = *(const f32x4*)p;
    f32x4 b = *(const f32x4*)(p + 4);
    bf16x8 r;
#pragma unroll
    for (int j = 0; j < 4; ++j) {
      r[j] = (__bf16)a[j];
      r[4 + j] = (__bf16)b[j];
    }
    *(bf16x8*)(out + (size_t)i * 8) = r;
  }
}

// ---------------- bf16 GEMM: C = A @ B^T + bias ----------------
// 2-phase double-buffered, one barrier per K-step. LDS rows are 64 B =
// 4 x 16 B chunks; chunk XOR-swizzle c ^= (row&3) ^ ((row>>2)&3) applied on
// BOTH sides (pre-swizzled GLOBAL source addr for global_load_lds, which
// writes linearly; swizzled chunk on ds_read) -> conflict-free fragment
// reads (each 8-lane service group covers all 32 banks).
// BM x BN tile, BK=32, 4 waves as 2x2, wave tile (BM/2)x(BN/2).
// MODE 0: f32 out. MODE 1: QKV pack (Q row-major; K/V fragment-linear tiles).
template <int BM, int BN, int MODE>
__global__ __launch_bounds__(256, 6) void gemm_bt(
    const u16* __restrict__ A, const u16* __restrict__ B,
    const float* __restrict__ bias, float* __restrict__ Cout,
    __bf16* __restrict__ qb, __bf16* __restrict__ kp, __bf16* __restrict__ vp,
    int M, int N, int K, int mtiles) {
  constexpr int MREP = BM / 32;  // per-wave M fragments
  constexpr int NREP = BN / 32;  // per-wave N fragments
  constexpr int LA = BM / 64;    // A stage loads/thread
  constexpr int LB = BN / 64;    // B stage loads/thread
  __shared__ u16 lA[2 * BM * 32];
  __shared__ u16 lB[2 * BN * 32];
  const int tid = threadIdx.x;
  const int wid = tid >> 6;
  const int lane = tid & 63;
  const int lr = lane & 15;
  const int lg = lane >> 4;

  // bijective XCD swizzle (gridDim.x % 8 == 0)
  const int nwg = gridDim.x;
  const int lid = blockIdx.x;
  const int sw = (lid & 7) * (nwg >> 3) + (lid >> 3);
  const int bm = (sw % mtiles) * BM;
  const int bn = (sw / mtiles) * BN;

  const int wm = (wid >> 1) * (BM / 2);
  const int wn = (wid & 1) * (BN / 2);

  // swizzle constants (per-lane / per-thread, loop-invariant)
  const int ce_sw = (((tid & 3) ^ ((tid >> 2) & 3) ^ ((tid >> 4) & 3)) << 3);
  const int cR = ((lg ^ (lr & 3) ^ ((lr >> 2) & 3)) << 3);

  f32x4 acc[MREP][NREP] = {};

  auto stage = [&](int bf, int kt) {
    char* baseA = (char*)lA + bf * (BM * 64);
    char* baseB = (char*)lB + bf * (BN * 64);
#pragma unroll
    for (int j = 0; j < LA; ++j) {
      int off = (tid + j * 256) * 16;
      gll16(A + (size_t)(bm + (off >> 6)) * K + kt + ce_sw, baseA + off);
    }
#pragma unroll
    for (int j = 0; j < LB; ++j) {
      int off = (tid + j * 256) * 16;
      gll16(B + (size_t)(bn + (off >> 6)) * K + kt + ce_sw, baseB + off);
    }
  };

  int buf = 0;
  stage(0, 0);
  for (int kt = 0; kt < K; kt += 32) {
    __syncthreads();  // buf staged & visible (implicit vmcnt/lgkm drain)
    if (kt + 32 < K) stage(buf ^ 1, kt + 32);  // overlaps compute below
    const u16* cA = lA + buf * BM * 32;
    const u16* cB = lB + buf * BN * 32;
    bf16x8 af[MREP], bfr[NREP];
#pragma unroll
    for (int mt = 0; mt < MREP; ++mt)
      af[mt] = *(const bf16x8*)&cA[(wm + mt * 16 + lr) * 32 + cR];
#pragma unroll
    for (int nt = 0; nt < NREP; ++nt)
      bfr[nt] = *(const bf16x8*)&cB[(wn + nt * 16 + lr) * 32 + cR];
#pragma unroll
    for (int mt = 0; mt < MREP; ++mt)
#pragma unroll
      for (int nt = 0; nt < NREP; ++nt)
        acc[mt][nt] = mfma16(af[mt], bfr[nt], acc[mt][nt]);
    buf ^= 1;
  }

#pragma unroll
  for (int nt = 0; nt < NREP; ++nt) {
    int col = bn + wn + nt * 16 + lr;
    float bv = bias[col];
#pragma unroll
    for (int mt = 0; mt < MREP; ++mt) {
#pragma unroll
      for (int r = 0; r < 4; ++r) {
        int row = bm + wm + mt * 16 + lg * 4 + r;
        float val = acc[mt][nt][r] + bv;
        if (MODE == 0) {
          Cout[(size_t)row * N + col] = val;
        } else {
          __bf16 bx = (__bf16)val;
          int b = row >> 11, s = row & 2047;
          int third = col >> 10, hd = col & 1023;
          int h = hd >> 6, d = hd & 63;
          if (third == 0) {
            qb[(size_t)row * 1024 + hd] = bx;
          } else {
            int bh = b * 16 + h, t = s >> 6, sr = s & 63;
            size_t tb = ((size_t)(bh * 32 + t)) * 4096;
            if (third == 1)
              kp[tb + (sr >> 4) * 1024 + (d >> 5) * 512 + ((d >> 3) & 3) * 128 +
                 (sr & 15) * 8 + (d & 7)] = bx;
            else
              vp[tb + (d >> 4) * 1024 + (sr >> 5) * 512 + ((sr >> 3) & 3) * 128 +
                 (d & 15) * 8 + (sr & 7)] = bx;
          }
        }
      }
    }
  }
}

// ---------------- fused causal+ALiBi flash attention ----------------
// 4096 independent 1-wave blocks: one 16-row qtile (a16 = 0..127 per bh) each,
// launched big-first for dynamic load balance. No barriers, no KV LDS.
// K/V fragments read as contiguous 1 KB loads from fragment-linear tiles
// (L2-resident: 4 bh per XCD = 2 MB). Defer-max online softmax (THR=8 log2).
__global__ __launch_bounds__(64, 4) void attn_kernel(
    const __bf16* __restrict__ qb, const __bf16* __restrict__ kp,
    const __bf16* __restrict__ vp, __bf16* __restrict__ aout) {
  __shared__ __bf16 p_lds[16][72];
  const int lane = threadIdx.x & 63;
  const int lr = lane & 15;
  const int lg = lane >> 4;

  const int lid = blockIdx.x;
  const int xcd = lid & 7;
  const int rest = lid >> 3;            // 0..511
  const int bh = xcd * 4 + (rest & 3);  // 4 bh per XCD
  const int a16 = 127 - (rest >> 2);    // qtile, descending (big blocks first)
  const int b = bh >> 4, h = bh & 15;
  const int qr0 = a16 * 16;
  const int ntl = (a16 >> 2) + 1;  // kv tiles needed

  const float LOG2E = 1.4426950408889634f;
  const float c1 = 0.125f * LOG2E;
  const float c2 = exp2f(-(float)(h + 1) * 0.5f) * LOG2E;

  bf16x8 ones;
#pragma unroll
  for (int j = 0; j < 8; ++j) ones[j] = (__bf16)1.0f;

  const u16* ktiles = (const u16*)kp + (size_t)bh * 32 * 4096;
  const u16* vtiles = (const u16*)vp + (size_t)bh * 32 * 4096;

  const __bf16* qrow = qb + (size_t)(b * 2048 + qr0 + lr) * 1024 + h * 64;
  bf16x8 qf0 = *(const bf16x8*)(qrow + lg * 8);
  bf16x8 qf1 = *(const bf16x8*)(qrow + 32 + lg * 8);

  float m[4], l[4], cq[4];
  f32x4 o[4];
#pragma unroll
  for (int r = 0; r < 4; ++r) {
    m[r] = 0.f;  // defer-max: safe start, violations handled below
    l[r] = 0.f;
    cq[r] = c2 * (float)(qr0 + lg * 4 + r);
  }
#pragma unroll
  for (int dt = 0; dt < 4; ++dt) o[dt] = (f32x4){0.f, 0.f, 0.f, 0.f};

  for (int t = 0; t < ntl; ++t) {
    const u16* kb = ktiles + (size_t)t * 4096;
    const u16* vb = vtiles + (size_t)t * 4096;
    const int kv = t * 64;
    const bool last = (t == ntl - 1);

    bf16x8 ka[8], va[8];
#pragma unroll
    for (int j = 0; j < 8; ++j)
      ka[j] = *(const bf16x8*)(kb + j * 512 + lane * 8);
#pragma unroll
    for (int j = 0; j < 8; ++j)
      va[j] = *(const bf16x8*)(vb + j * 512 + lane * 8);

    // ---- QK^T ----
    f32x4 s[4];
#pragma unroll
    for (int nt = 0; nt < 4; ++nt) {
      f32x4 tt = (f32x4){0.f, 0.f, 0.f, 0.f};
      tt = mfma16(qf0, ka[nt * 2], tt);
      tt = mfma16(qf1, ka[nt * 2 + 1], tt);
      s[nt] = tt;
    }

    // ---- logits (log2 domain) ----
#pragma unroll
    for (int nt = 0; nt < 4; ++nt) {
      float bnt = c2 * (float)(kv + nt * 16 + lr);
#pragma unroll
      for (int r = 0; r < 4; ++r)
        s[nt][r] = __builtin_fmaf(s[nt][r], c1, bnt - cq[r]);
    }
    if (last) {  // diagonal tile: causal mask
#pragma unroll
      for (int nt = 0; nt < 4; ++nt) {
        float kf = (float)(kv + nt * 16 + lr);
#pragma unroll
        for (int r = 0; r < 4; ++r) {
          float qi = (float)(qr0 + lg * 4 + r);
          if (kf > qi) s[nt][r] = -1e30f;
        }
      }
    }

    // ---- defer-max check (no cross-lane in common path) ----
    float pm[4];
#pragma unroll
    for (int r = 0; r < 4; ++r)
      pm[r] = fmaxf(fmaxf(s[0][r], s[1][r]), fmaxf(s[2][r], s[3][r]));
    bool ok = (pm[0] <= m[0] + 8.f) && (pm[1] <= m[1] + 8.f) &&
              (pm[2] <= m[2] + 8.f) && (pm[3] <= m[3] + 8.f);
    if (!__all(ok)) {  // rare: full reduce + rescale
#pragma unroll
      for (int r = 0; r < 4; ++r)
#pragma unroll
        for (int d = 1; d < 16; d <<= 1)
          pm[r] = fmaxf(pm[r], __shfl_xor(pm[r], d));
#pragma unroll
      for (int r = 0; r < 4; ++r) {
        float mn = fmaxf(m[r], pm[r]);
        float fac = __builtin_amdgcn_exp2f(m[r] - mn);
        m[r] = mn;
        l[r] *= fac;
#pragma unroll
        for (int dt = 0; dt < 4; ++dt) o[dt][r] *= fac;
      }
    }

    // ---- P = exp2(s - m), store to wave-private LDS ----
#pragma unroll
    for (int nt = 0; nt < 4; ++nt)
#pragma unroll
      for (int r = 0; r < 4; ++r) {
        float e = __builtin_amdgcn_exp2f(s[nt][r] - m[r]);
        p_lds[lg * 4 + r][nt * 16 + lr] = (__bf16)e;
      }

    // wave-private LDS: compiler orders via lgkmcnt, no barrier needed
    bf16x8 pa0 = *(const bf16x8*)&p_lds[lr][lg * 8];
    bf16x8 pa1 = *(const bf16x8*)&p_lds[lr][32 + lg * 8];

    // ---- row-sum via ones-MFMA ----
    {
      f32x4 tt = (f32x4){0.f, 0.f, 0.f, 0.f};
      tt = mfma16(pa0, ones, tt);
      tt = mfma16(pa1, ones, tt);
#pragma unroll
      for (int r = 0; r < 4; ++r) l[r] += tt[r];
    }

    // ---- PV ----
#pragma unroll
    for (int dt = 0; dt < 4; ++dt) {
      o[dt] = mfma16(pa0, va[dt * 2], o[dt]);
      o[dt] = mfma16(pa1, va[dt * 2 + 1], o[dt]);
    }
  }

  // ---- epilogue ----
#pragma unroll
  for (int dt = 0; dt < 4; ++dt)
#pragma unroll
    for (int r = 0; r < 4; ++r) {
      float val = o[dt][r] / l[r];
      aout[(size_t)(b * 2048 + qr0 + lg * 4 + r) * 1024 + h * 64 + dt * 16 + lr] =
          (__bf16)val;
    }
}

extern "C" void kernel_launch(void* const* d_in, const int* in_sizes, int n_in,
                              void* d_out, int out_size, void* d_ws, size_t ws_size,
                              hipStream_t stream) {
  (void)in_sizes; (void)n_in; (void)out_size; (void)ws_size;
  const float* x = (const float*)d_in[0];
  const float* Wp = (const float*)d_in[1];
  const float* bp = (const float*)d_in[2];
  const float* Wo = (const float*)d_in[3];
  const float* bo = (const float*)d_in[4];
  float* out = (float*)d_out;

  char* ws = (char*)d_ws;
  u16* xb  = (u16*)(ws);                        // 8 MB  x bf16 [4096,1024]
  u16* wpb = (u16*)(ws + (size_t)(8u << 20));   // 6 MB  W_packed bf16
  u16* wob = (u16*)(ws + (size_t)(14u << 20));  // 2 MB  W_out bf16
  u16* qbp = (u16*)(ws + (size_t)(16u << 20));  // 8 MB  Q [4096,1024]
  u16* kpp = (u16*)(ws + (size_t)(24u << 20));  // 8 MB  K fragment tiles
  u16* vpp = (u16*)(ws + (size_t)(32u << 20));  // 8 MB  V fragment tiles
  u16* ab  = xb;  // attention output reuses x_bf16 space

  cvt_kernel<<<2048, 256, 0, stream>>>(x, (__bf16*)xb, 4096 * 1024 / 8);
  cvt_kernel<<<1536, 256, 0, stream>>>(Wp, (__bf16*)wpb, 3072 * 1024 / 8);
  cvt_kernel<<<512, 256, 0, stream>>>(Wo, (__bf16*)wob, 1024 * 1024 / 8);
  // gemm1: 128x64 tiles -> grid 32*48 = 1536 blocks (6/CU)
  gemm_bt<128, 64, 1><<<1536, 256, 0, stream>>>(
      xb, wpb, bp, nullptr, (__bf16*)qbp, (__bf16*)kpp, (__bf16*)vpp,
      4096, 3072, 1024, 32);
  attn_kernel<<<4096, 64, 0, stream>>>(
      (const __bf16*)qbp, (const __bf16*)kpp, (const __bf16*)vpp, (__bf16*)ab);
  // gemm2: 128x64 tiles -> grid 32*16 = 512 blocks (2/CU)
  gemm_bt<128, 64, 0><<<512, 256, 0, stream>>>(
      ab, wob, bo, out, nullptr, nullptr, nullptr, 4096, 1024, 1024, 32);
}

// Round 9
// 120.481 us; speedup vs baseline: 1.0520x; 1.0520x over previous
//
#include <hip/hip_runtime.h>

typedef float f32x4 __attribute__((ext_vector_type(4)));
typedef __bf16 bf16x8 __attribute__((ext_vector_type(8)));
typedef unsigned short u16;

__device__ __forceinline__ f32x4 mfma16(bf16x8 a, bf16x8 b, f32x4 c) {
  return __builtin_amdgcn_mfma_f32_16x16x32_bf16(a, b, c, 0, 0, 0);
}

__device__ __forceinline__ void gll16(const void* g, void* l) {
  __builtin_amdgcn_global_load_lds(
      (const __attribute__((address_space(1))) void*)g,
      (__attribute__((address_space(3))) void*)l, 16, 0, 0);
}

// ---------------- f32 -> bf16 convert ----------------
__global__ void cvt_kernel(const float* __restrict__ in, __bf16* __restrict__ out, int n8) {
  int idx = blockIdx.x * blockDim.x + threadIdx.x;
  int stride = gridDim.x * blockDim.x;
  for (int i = idx; i < n8; i += stride) {
    const float* p = in + (size_t)i * 8;
    f32x4 a = *(const f32x4*)p;
    f32x4 b = *(const f32x4*)(p + 4);
    bf16x8 r;
#pragma unroll
    for (int j = 0; j < 4; ++j) {
      r[j] = (__bf16)a[j];
      r[4 + j] = (__bf16)b[j];
    }
    *(bf16x8*)(out + (size_t)i * 8) = r;
  }
}

// ---------------- bf16 GEMM: C = A @ B^T + bias ----------------
// T4 counted-vmcnt pipeline: raw s_barrier (no vmcnt/lgkm drain), DEPTH=3
// LDS buffers, 4 gll16/wave/step. Steady state: 12 loads in flight, wait
// vmcnt(8) retires only the current tile's 4 -> prefetch spans barriers.
// 128x128 tile, BK=32, 4 waves as 2x2, wave tile 64x64 (16 MFMA : 8 ds_read).
// MODE 0: f32 out. MODE 1: QKV pack (Q row-major; K/V fragment-linear tiles).
template <int BM, int BN, int MODE>
__global__ __launch_bounds__(256, 3) void gemm_bt(
    const u16* __restrict__ A, const u16* __restrict__ B,
    const float* __restrict__ bias, float* __restrict__ Cout,
    __bf16* __restrict__ qb, __bf16* __restrict__ kp, __bf16* __restrict__ vp,
    int M, int N, int K, int mtiles) {
  constexpr int MREP = BM / 32;  // per-wave M fragments
  constexpr int NREP = BN / 32;  // per-wave N fragments
  constexpr int LA = BM / 64;    // A stage loads/thread
  constexpr int LB = BN / 64;    // B stage loads/thread
  static_assert(LA + LB == 4, "vmcnt literals assume 4 loads/wave/step");
  __shared__ u16 lA[3 * BM * 32];
  __shared__ u16 lB[3 * BN * 32];
  const int tid = threadIdx.x;
  const int wid = tid >> 6;
  const int lane = tid & 63;
  const int lr = lane & 15;
  const int lg = lane >> 4;

  // bijective XCD swizzle (gridDim.x % 8 == 0)
  const int nwg = gridDim.x;
  const int lid = blockIdx.x;
  const int sw = (lid & 7) * (nwg >> 3) + (lid >> 3);
  const int bm = (sw % mtiles) * BM;
  const int bn = (sw / mtiles) * BN;

  const int wm = (wid >> 1) * (BM / 2);
  const int wn = (wid & 1) * (BN / 2);

  f32x4 acc[MREP][NREP] = {};

  auto stage = [&](int bf, int t) {
    const int kt = t * 32;
    char* baseA = (char*)lA + bf * (BM * 64);
    char* baseB = (char*)lB + bf * (BN * 64);
#pragma unroll
    for (int j = 0; j < LA; ++j) {
      int off = (tid + j * 256) * 16;
      gll16(A + (size_t)(bm + (off >> 6)) * K + kt + ((off & 63) >> 1),
            baseA + off);
    }
#pragma unroll
    for (int j = 0; j < LB; ++j) {
      int off = (tid + j * 256) * 16;
      gll16(B + (size_t)(bn + (off >> 6)) * K + kt + ((off & 63) >> 1),
            baseB + off);
    }
  };

  const int T = K / 32;  // 32 for both GEMMs; T >= 3 required
  stage(0, 0);
  stage(1, 1);
  stage(2, 2);

  for (int t = 0; t < T; ++t) {
    const int rem = T - 1 - t;
    // counted wait: retire ONLY the current tile's 4 loads; rest stay in flight
    if (rem >= 2)
      asm volatile("s_waitcnt vmcnt(8)" ::: "memory");
    else if (rem == 1)
      asm volatile("s_waitcnt vmcnt(4)" ::: "memory");
    else
      asm volatile("s_waitcnt vmcnt(0)" ::: "memory");
    __builtin_amdgcn_s_barrier();  // all waves' tile-t quarters now visible

    const u16* cA = lA + (t % 3) * BM * 32;
    const u16* cB = lB + (t % 3) * BN * 32;
    bf16x8 af[MREP], bfr[NREP];
#pragma unroll
    for (int mt = 0; mt < MREP; ++mt)
      af[mt] = *(const bf16x8*)&cA[(wm + mt * 16 + lr) * 32 + lg * 8];
#pragma unroll
    for (int nt = 0; nt < NREP; ++nt)
      bfr[nt] = *(const bf16x8*)&cB[(wn + nt * 16 + lr) * 32 + lg * 8];
#pragma unroll
    for (int mt = 0; mt < MREP; ++mt)
#pragma unroll
      for (int nt = 0; nt < NREP; ++nt)
        acc[mt][nt] = mfma16(af[mt], bfr[nt], acc[mt][nt]);

    __builtin_amdgcn_sched_barrier(0);  // pin: reads complete before restage
    __builtin_amdgcn_s_barrier();       // all waves done reading buf t%3
    if (t + 3 < T) stage(t % 3, t + 3);
  }

#pragma unroll
  for (int nt = 0; nt < NREP; ++nt) {
    int col = bn + wn + nt * 16 + lr;
    float bv = bias[col];
#pragma unroll
    for (int mt = 0; mt < MREP; ++mt) {
#pragma unroll
      for (int r = 0; r < 4; ++r) {
        int row = bm + wm + mt * 16 + lg * 4 + r;
        float val = acc[mt][nt][r] + bv;
        if (MODE == 0) {
          Cout[(size_t)row * N + col] = val;
        } else {
          __bf16 bx = (__bf16)val;
          int b = row >> 11, s = row & 2047;
          int third = col >> 10, hd = col & 1023;
          int h = hd >> 6, d = hd & 63;
          if (third == 0) {
            qb[(size_t)row * 1024 + hd] = bx;
          } else {
            int bh = b * 16 + h, t2 = s >> 6, sr = s & 63;
            size_t tb = ((size_t)(bh * 32 + t2)) * 4096;
            if (third == 1)
              kp[tb + (sr >> 4) * 1024 + (d >> 5) * 512 + ((d >> 3) & 3) * 128 +
                 (sr & 15) * 8 + (d & 7)] = bx;
            else
              vp[tb + (d >> 4) * 1024 + (sr >> 5) * 512 + ((sr >> 3) & 3) * 128 +
                 (d & 15) * 8 + (sr & 7)] = bx;
          }
        }
      }
    }
  }
}

// ---------------- fused causal+ALiBi flash attention ----------------
// 4096 independent 1-wave blocks: one 16-row qtile (a16 = 0..127 per bh) each,
// launched big-first for dynamic load balance. No barriers, no KV LDS.
// K/V fragments read as contiguous 1 KB loads from fragment-linear tiles
// (L2-resident: 4 bh per XCD = 2 MB). Defer-max online softmax (THR=8 log2).
__global__ __launch_bounds__(64, 4) void attn_kernel(
    const __bf16* __restrict__ qb, const __bf16* __restrict__ kp,
    const __bf16* __restrict__ vp, __bf16* __restrict__ aout) {
  __shared__ __bf16 p_lds[16][72];
  const int lane = threadIdx.x & 63;
  const int lr = lane & 15;
  const int lg = lane >> 4;

  const int lid = blockIdx.x;
  const int xcd = lid & 7;
  const int rest = lid >> 3;            // 0..511
  const int bh = xcd * 4 + (rest & 3);  // 4 bh per XCD
  const int a16 = 127 - (rest >> 2);    // qtile, descending (big blocks first)
  const int b = bh >> 4, h = bh & 15;
  const int qr0 = a16 * 16;
  const int ntl = (a16 >> 2) + 1;  // kv tiles needed

  const float LOG2E = 1.4426950408889634f;
  const float c1 = 0.125f * LOG2E;
  const float c2 = exp2f(-(float)(h + 1) * 0.5f) * LOG2E;

  bf16x8 ones;
#pragma unroll
  for (int j = 0; j < 8; ++j) ones[j] = (__bf16)1.0f;

  const u16* ktiles = (const u16*)kp + (size_t)bh * 32 * 4096;
  const u16* vtiles = (const u16*)vp + (size_t)bh * 32 * 4096;

  const __bf16* qrow = qb + (size_t)(b * 2048 + qr0 + lr) * 1024 + h * 64;
  bf16x8 qf0 = *(const bf16x8*)(qrow + lg * 8);
  bf16x8 qf1 = *(const bf16x8*)(qrow + 32 + lg * 8);

  float m[4], l[4], cq[4];
  f32x4 o[4];
#pragma unroll
  for (int r = 0; r < 4; ++r) {
    m[r] = 0.f;  // defer-max: safe start, violations handled below
    l[r] = 0.f;
    cq[r] = c2 * (float)(qr0 + lg * 4 + r);
  }
#pragma unroll
  for (int dt = 0; dt < 4; ++dt) o[dt] = (f32x4){0.f, 0.f, 0.f, 0.f};

  for (int t = 0; t < ntl; ++t) {
    const u16* kb = ktiles + (size_t)t * 4096;
    const u16* vb = vtiles + (size_t)t * 4096;
    const int kv = t * 64;
    const bool last = (t == ntl - 1);

    bf16x8 ka[8], va[8];
#pragma unroll
    for (int j = 0; j < 8; ++j)
      ka[j] = *(const bf16x8*)(kb + j * 512 + lane * 8);
#pragma unroll
    for (int j = 0; j < 8; ++j)
      va[j] = *(const bf16x8*)(vb + j * 512 + lane * 8);

    // ---- QK^T ----
    f32x4 s[4];
#pragma unroll
    for (int nt = 0; nt < 4; ++nt) {
      f32x4 tt = (f32x4){0.f, 0.f, 0.f, 0.f};
      tt = mfma16(qf0, ka[nt * 2], tt);
      tt = mfma16(qf1, ka[nt * 2 + 1], tt);
      s[nt] = tt;
    }

    // ---- logits (log2 domain) ----
#pragma unroll
    for (int nt = 0; nt < 4; ++nt) {
      float bnt = c2 * (float)(kv + nt * 16 + lr);
#pragma unroll
      for (int r = 0; r < 4; ++r)
        s[nt][r] = __builtin_fmaf(s[nt][r], c1, bnt - cq[r]);
    }
    if (last) {  // diagonal tile: causal mask
#pragma unroll
      for (int nt = 0; nt < 4; ++nt) {
        float kf = (float)(kv + nt * 16 + lr);
#pragma unroll
        for (int r = 0; r < 4; ++r) {
          float qi = (float)(qr0 + lg * 4 + r);
          if (kf > qi) s[nt][r] = -1e30f;
        }
      }
    }

    // ---- defer-max check (no cross-lane in common path) ----
    float pm[4];
#pragma unroll
    for (int r = 0; r < 4; ++r)
      pm[r] = fmaxf(fmaxf(s[0][r], s[1][r]), fmaxf(s[2][r], s[3][r]));
    bool ok = (pm[0] <= m[0] + 8.f) && (pm[1] <= m[1] + 8.f) &&
              (pm[2] <= m[2] + 8.f) && (pm[3] <= m[3] + 8.f);
    if (!__all(ok)) {  // rare: full reduce + rescale
#pragma unroll
      for (int r = 0; r < 4; ++r)
#pragma unroll
        for (int d = 1; d < 16; d <<= 1)
          pm[r] = fmaxf(pm[r], __shfl_xor(pm[r], d));
#pragma unroll
      for (int r = 0; r < 4; ++r) {
        float mn = fmaxf(m[r], pm[r]);
        float fac = __builtin_amdgcn_exp2f(m[r] - mn);
        m[r] = mn;
        l[r] *= fac;
#pragma unroll
        for (int dt = 0; dt < 4; ++dt) o[dt][r] *= fac;
      }
    }

    // ---- P = exp2(s - m), store to wave-private LDS ----
#pragma unroll
    for (int nt = 0; nt < 4; ++nt)
#pragma unroll
      for (int r = 0; r < 4; ++r) {
        float e = __builtin_amdgcn_exp2f(s[nt][r] - m[r]);
        p_lds[lg * 4 + r][nt * 16 + lr] = (__bf16)e;
      }

    // wave-private LDS: compiler orders via lgkmcnt, no barrier needed
    bf16x8 pa0 = *(const bf16x8*)&p_lds[lr][lg * 8];
    bf16x8 pa1 = *(const bf16x8*)&p_lds[lr][32 + lg * 8];

    // ---- row-sum via ones-MFMA ----
    {
      f32x4 tt = (f32x4){0.f, 0.f, 0.f, 0.f};
      tt = mfma16(pa0, ones, tt);
      tt = mfma16(pa1, ones, tt);
#pragma unroll
      for (int r = 0; r < 4; ++r) l[r] += tt[r];
    }

    // ---- PV ----
#pragma unroll
    for (int dt = 0; dt < 4; ++dt) {
      o[dt] = mfma16(pa0, va[dt * 2], o[dt]);
      o[dt] = mfma16(pa1, va[dt * 2 + 1], o[dt]);
    }
  }

  // ---- epilogue ----
#pragma unroll
  for (int dt = 0; dt < 4; ++dt)
#pragma unroll
    for (int r = 0; r < 4; ++r) {
      float val = o[dt][r] / l[r];
      aout[(size_t)(b * 2048 + qr0 + lg * 4 + r) * 1024 + h * 64 + dt * 16 + lr] =
          (__bf16)val;
    }
}

extern "C" void kernel_launch(void* const* d_in, const int* in_sizes, int n_in,
                              void* d_out, int out_size, void* d_ws, size_t ws_size,
                              hipStream_t stream) {
  (void)in_sizes; (void)n_in; (void)out_size; (void)ws_size;
  const float* x = (const float*)d_in[0];
  const float* Wp = (const float*)d_in[1];
  const float* bp = (const float*)d_in[2];
  const float* Wo = (const float*)d_in[3];
  const float* bo = (const float*)d_in[4];
  float* out = (float*)d_out;

  char* ws = (char*)d_ws;
  u16* xb  = (u16*)(ws);                        // 8 MB  x bf16 [4096,1024]
  u16* wpb = (u16*)(ws + (size_t)(8u << 20));   // 6 MB  W_packed bf16
  u16* wob = (u16*)(ws + (size_t)(14u << 20));  // 2 MB  W_out bf16
  u16* qbp = (u16*)(ws + (size_t)(16u << 20));  // 8 MB  Q [4096,1024]
  u16* kpp = (u16*)(ws + (size_t)(24u << 20));  // 8 MB  K fragment tiles
  u16* vpp = (u16*)(ws + (size_t)(32u << 20));  // 8 MB  V fragment tiles
  u16* ab  = xb;  // attention output reuses x_bf16 space

  cvt_kernel<<<2048, 256, 0, stream>>>(x, (__bf16*)xb, 4096 * 1024 / 8);
  cvt_kernel<<<1536, 256, 0, stream>>>(Wp, (__bf16*)wpb, 3072 * 1024 / 8);
  cvt_kernel<<<512, 256, 0, stream>>>(Wo, (__bf16*)wob, 1024 * 1024 / 8);
  // gemm1: 128x128 tiles -> grid 32*24 = 768 blocks (3/CU)
  gemm_bt<128, 128, 1><<<768, 256, 0, stream>>>(
      xb, wpb, bp, nullptr, (__bf16*)qbp, (__bf16*)kpp, (__bf16*)vpp,
      4096, 3072, 1024, 32);
  attn_kernel<<<4096, 64, 0, stream>>>(
      (const __bf16*)qbp, (const __bf16*)kpp, (const __bf16*)vpp, (__bf16*)ab);
  // gemm2: 128x128 tiles -> grid 32*8 = 256 blocks (1/CU, self-pipelined)
  gemm_bt<128, 128, 0><<<256, 256, 0, stream>>>(
      ab, wob, bo, out, nullptr, nullptr, nullptr, 4096, 1024, 1024, 32);
}